// Round 7
// baseline (269.611 us; speedup 1.0000x reference)
//
#include <hip/hip_runtime.h>
#include <hip/hip_bf16.h>

constexpr int BN = 8, HH = 512, WW = 512;
constexpr int PIX = HH * WW;
constexpr float EPSF = 1e-4f;

__device__ __forceinline__ float b2f(__hip_bfloat16 x) { return __bfloat162float(x); }
__device__ __forceinline__ __hip_bfloat16 f2b(float x) { return __float2bfloat16(x); }
__device__ __forceinline__ unsigned short bfbits(float x) {
    union { __hip_bfloat16 b; unsigned short u; } cv; cv.b = f2b(x); return cv.u;
}

typedef __attribute__((ext_vector_type(8))) short bf16x8;   // MFMA A/B frag (4 VGPRs)
typedef __attribute__((ext_vector_type(4))) float f32x4;    // MFMA C/D frag

// ---- workspace float offsets (small region) ----
constexpr int OFF_TOT = 0;       // 8*16 per-image channel totals (atomics)
constexpr int OFF_ROW0 = 128;
constexpr int OFF_ROW1 = 256;
constexpr int OFF_COL0 = 384;
constexpr int OFF_COL1 = 512;
constexpr int OFF_COR = 640;     // corners [b][hi][wi][16]
constexpr int OFF_WR  = 2048;    // A-fragment weights hi(2560 bf16) + lo(2560 bf16)
constexpr int OFF_EH  = 4608;    // 8*37
constexpr int OFF_CH  = 5120;    // 8*37
// ---- big buffers: only tpl now (xg eliminated; computed on the fly in horiz) ----
constexpr size_t OFF_TPB = 65536;                          // tpl fp32 (4 planes)
constexpr size_t TP_BYTES = (size_t)4 * BN * PIX * 4;      // 33,554,432
constexpr size_t WS_NEEDED = OFF_TPB + TP_BYTES;           // ~33.6 MB (134 MB proven)

// ---------------- prep: zero atomic slots, swizzle w2 into hi/lo A-fragments ----------------
// hi = rn-bf16(w), lo = rn-bf16(w - hi): split keeps mean(s) at ~fp32 accuracy (round-4 lesson:
// bf16-only w2 flips the discontinuous ceil() in fs -> pi-flips in Hf).
__global__ void prep_kernel(const float* __restrict__ w2, float* __restrict__ wsf) {
    int t = threadIdx.x;
    for (int i = t; i < 640; i += 256) wsf[i] = 0.f;
    unsigned short* ab = (unsigned short*)(wsf + OFF_WR);
    for (int idx = t; idx < 5120; idx += 256) {
        int part = idx / 2560;               // 0 = hi, 1 = lo
        int id = idx - part * 2560;
        int ks = id >> 9, rem = id & 511, lane = rem >> 3, j = id & 7;
        int oc = lane & 15, q = lane >> 4;
        int k = q * 8 + j;
        int tap = 2 * ks + (k >> 4), ic = k & 15;
        float val = (tap <= 8) ? w2[oc * 144 + ic * 9 + tap] : 0.f;
        float hv = b2f(f2b(val));
        ab[idx] = (part == 0) ? bfbits(val) : bfbits(val - hv);
    }
}

// conv1 for one pixel given its 27-value receptive field -> packed bf16 pair words
__device__ __forceinline__ void conv1_px(const float v[27], const float* __restrict__ w1,
                                         const float* __restrict__ b1, unsigned int u[8]) {
    float o[16];
#pragma unroll
    for (int oc = 0; oc < 16; oc++) {
        float a = b1[oc];
#pragma unroll
        for (int j = 0; j < 27; j++) a += v[j] * w1[oc * 27 + j];   // uniform -> s_load batches
        o[oc] = a / (1.f + __expf(-a));
    }
#pragma unroll
    for (int k = 0; k < 8; k++)
        u[k] = (unsigned int)bfbits(o[2 * k]) | ((unsigned int)bfbits(o[2 * k + 1]) << 16);
}

// ---------------- fused conv1+conv2(+RGB) with conv3-mean reduction ----------------
__global__ __launch_bounds__(256) void conv12_kernel(const float* __restrict__ batch,
                                                     const float* __restrict__ w1,
                                                     const float* __restrict__ b1,
                                                     const unsigned short* __restrict__ abuf,
                                                     const float* __restrict__ b2v,
                                                     const float* __restrict__ gcm,
                                                     float* __restrict__ wsf,
                                                     float* __restrict__ out) {
    __shared__ uint4 h1s[18 * 66 * 2];     // [(r*66+c)*2 + (half ^ ((c>>2)&1))], 38,016 B
    __shared__ float part[4][16];

    int tx = threadIdx.x;
    int lane = tx & 63, wave = tx >> 6;
    int n = lane & 15, q = lane >> 4;
    int w0 = blockIdx.x * 64, h0 = blockIdx.y * 16, b = blockIdx.z;
    bool edge = (blockIdx.x == 0) || (blockIdx.x == 7) || (blockIdx.y == 0) || (blockIdx.y == 31);

    union { uint4 u; bf16x8 v; } cv;
    bf16x8 ah[5], al[5];
    const uint4* ab4 = (const uint4*)abuf;
#pragma unroll
    for (int ks = 0; ks < 5; ks++) {
        cv.u = ab4[ks * 64 + lane];       ah[ks] = cv.v;
        cv.u = ab4[320 + ks * 64 + lane]; al[ks] = cv.v;
    }

    // ---- phase 1: conv1 into LDS (66x18 window incl. 1-px halo) ----
    const float* pb = batch + (size_t)(b * 3) * PIX;
    for (int i = tx; i < 18 * 66; i += 256) {
        int r = i / 66, c = i - r * 66;
        int gh = h0 - 1 + r, gw = w0 - 1 + c;
        unsigned int u[8];
        if (!edge) {
            // interior: no bounds checks, constant-offset loads
            const float* p0 = pb + (size_t)(gh - 1) * WW + (gw - 1);
            float v[27];
#pragma unroll
            for (int ic = 0; ic < 3; ic++)
#pragma unroll
                for (int kh = 0; kh < 3; kh++)
#pragma unroll
                    for (int kw = 0; kw < 3; kw++)
                        v[ic * 9 + kh * 3 + kw] = p0[(size_t)ic * PIX + kh * WW + kw];
            conv1_px(v, w1, b1, u);
        } else if (gh >= 0 && gh < HH && gw >= 0 && gw < WW) {
            float v[27];
#pragma unroll
            for (int ic = 0; ic < 3; ic++) {
                const float* p = pb + (size_t)ic * PIX;
#pragma unroll
                for (int kh = 0; kh < 3; kh++) {
                    int hh = gh + kh - 1;
#pragma unroll
                    for (int kw = 0; kw < 3; kw++) {
                        int ww = gw + kw - 1;
                        float x = 0.f;
                        if (hh >= 0 && hh < HH && ww >= 0 && ww < WW) x = p[hh * WW + ww];
                        v[ic * 9 + kh * 3 + kw] = x;
                    }
                }
            }
            conv1_px(v, w1, b1, u);
        } else {
#pragma unroll
            for (int k = 0; k < 8; k++) u[k] = 0u;
        }
        int swz = (c >> 2) & 1;
        int base = i * 2;
        h1s[base + swz]       = make_uint4(u[0], u[1], u[2], u[3]);
        h1s[base + (swz ^ 1)] = make_uint4(u[4], u[5], u[6], u[7]);
    }

    // ---- phase 1b: RGB_order for the 64x16 center region ----
    for (int j = tx; j < 1024; j += 256) {
        int rr = j >> 6, ccx = j & 63;
        size_t p = (size_t)(h0 + rr) * WW + (w0 + ccx);
        float v0 = pb[p], v1 = pb[(size_t)PIX + p], v2 = pb[2 * (size_t)PIX + p];
        int mx  = (v0 >= v1 && v0 >= v2) ? 0 : ((v1 >= v2) ? 1 : 2);
        int mx2 = (v2 >= v1 && v2 >= v0) ? 2 : ((v1 >= v0) ? 1 : 0);
        int mn  = (v0 <= v1 && v0 <= v2) ? 0 : ((v1 <= v2) ? 1 : 2);
        int mn2 = (v2 <= v1 && v2 <= v0) ? 2 : ((v1 <= v0) ? 1 : 0);
#pragma unroll
        for (int c = 0; c < 3; c++) {
            float r = 0.5f * ((float)(c == mx) + (float)(c == mx2))
                    - 0.5f * ((float)(c == mn) + (float)(c == mn2));
            out[(size_t)(b * 6 + 2 + c) * PIX + p] = r;
        }
    }
    __syncthreads();

    // ---- phase 2: conv2 MFMA from LDS; wave handles rows wave*4..wave*4+3 ----
    float tt[4] = {0, 0, 0, 0};
    float cs0[4] = {0, 0, 0, 0};
    float cs1[4] = {0, 0, 0, 0};
    for (int rloc = 0; rloc < 4; rloc++) {
        int row = wave * 4 + rloc;
        int grow = h0 + row;
        f32x4 acc[4] = {{0,0,0,0},{0,0,0,0},{0,0,0,0},{0,0,0,0}};
#pragma unroll
        for (int ks = 0; ks < 5; ks++) {
            int tap = 2 * ks + (q >> 1); if (tap > 8) tap = 8;
            int dh = tap / 3 - 1, dw = tap % 3 - 1;
            int half = q & 1;
            int lr = row + 1 + dh;
#pragma unroll
            for (int t = 0; t < 4; t++) {
                int c = 1 + dw + t * 16 + n;
                cv.u = h1s[(lr * 66 + c) * 2 + (half ^ ((c >> 2) & 1))];
                acc[t] = __builtin_amdgcn_mfma_f32_16x16x32_bf16(ah[ks], cv.v, acc[t], 0, 0, 0);
                acc[t] = __builtin_amdgcn_mfma_f32_16x16x32_bf16(al[ks], cv.v, acc[t], 0, 0, 0);
            }
        }
        float sv[4][4];
#pragma unroll
        for (int t = 0; t < 4; t++)
#pragma unroll
            for (int r = 0; r < 4; r++) {
                float a = acc[t][r] + b2v[q * 4 + r];
                sv[t][r] = a / (1.f + __expf(-a));
            }
#pragma unroll
        for (int r = 0; r < 4; r++) tt[r] += sv[0][r] + sv[1][r] + sv[2][r] + sv[3][r];
        if (grow == 0 || grow == HH - 1) {
            int off = (grow == 0) ? OFF_ROW0 : OFF_ROW1;
#pragma unroll
            for (int r = 0; r < 4; r++) {
                float x = sv[0][r] + sv[1][r] + sv[2][r] + sv[3][r];
#pragma unroll
                for (int d = 1; d < 16; d <<= 1) x += __shfl_xor(x, d, 64);
                if (n == 0) atomicAdd(&wsf[off + b * 16 + q * 4 + r], x);
            }
        }
        if (blockIdx.x == 0 && n == 0)
#pragma unroll
            for (int r = 0; r < 4; r++) cs0[r] += sv[0][r];
        if (blockIdx.x == 7 && n == 15)
#pragma unroll
            for (int r = 0; r < 4; r++) cs1[r] += sv[3][r];
        if ((grow == 0 || grow == HH - 1)) {
            int hi = (grow == 0) ? 0 : 1;
            if (blockIdx.x == 0 && n == 0)
#pragma unroll
                for (int r = 0; r < 4; r++)
                    wsf[OFF_COR + ((b * 2 + hi) * 2 + 0) * 16 + q * 4 + r] = sv[0][r];
            if (blockIdx.x == 7 && n == 15)
#pragma unroll
                for (int r = 0; r < 4; r++)
                    wsf[OFF_COR + ((b * 2 + hi) * 2 + 1) * 16 + q * 4 + r] = sv[3][r];
        }
    }
    if (blockIdx.x == 0 && n == 0)
#pragma unroll
        for (int r = 0; r < 4; r++) atomicAdd(&wsf[OFF_COL0 + b * 16 + q * 4 + r], cs0[r]);
    if (blockIdx.x == 7 && n == 15)
#pragma unroll
        for (int r = 0; r < 4; r++) atomicAdd(&wsf[OFF_COL1 + b * 16 + q * 4 + r], cs1[r]);
#pragma unroll
    for (int r = 0; r < 4; r++) {
        float x = tt[r];
#pragma unroll
        for (int d = 1; d < 16; d <<= 1) x += __shfl_xor(x, d, 64);
        tt[r] = x;
    }
    if (n == 0)
#pragma unroll
        for (int r = 0; r < 4; r++) part[wave][q * 4 + r] = tt[r];
    __syncthreads();
    if (tx < 16)
        atomicAdd(&wsf[OFF_TOT + b * 16 + tx],
                  part[0][tx] + part[1][tx] + part[2][tx] + part[3][tx]);
}

// ---------------- filter: assemble mean via edge algebra, build separable taps ----------------
__global__ void filter_kernel(const float* __restrict__ w3, const float* __restrict__ b3,
                              float* __restrict__ wsf) {
    int b = blockIdx.x, t = threadIdx.x;   // 160 threads
    __shared__ float red[160];
    float val = 0.f;
    if (t < 144) {
        int ic = t / 9, tap = t % 9, kh = tap / 3, kw = tap % 3;
        float T = wsf[OFF_TOT + b * 16 + ic];
        int hi = -1, wi = -1;
        if (kh == 0) { T -= wsf[OFF_ROW1 + b * 16 + ic]; hi = 1; }
        else if (kh == 2) { T -= wsf[OFF_ROW0 + b * 16 + ic]; hi = 0; }
        if (kw == 0) { T -= wsf[OFF_COL1 + b * 16 + ic]; wi = 1; }
        else if (kw == 2) { T -= wsf[OFF_COL0 + b * 16 + ic]; wi = 0; }
        if (hi >= 0 && wi >= 0) T += wsf[OFF_COR + ((b * 2 + hi) * 2 + wi) * 16 + ic];
        val = w3[t] * T;
    }
    red[t] = val;
    __syncthreads();
    __shared__ float sh_mean;
    if (t == 0) {
        float S = 0.f;
        for (int i = 0; i < 144; i++) S += red[i];
        sh_mean = b3[0] + S * (1.f / (float)PIX);
    }
    __syncthreads();
    float scale = fminf(2.5f, fmaxf(-2.5f, sh_mean));
    float sd = exp2f(scale);
    float fs = ceilf(3.f * sd + 0.5f);
    float e = 0.f, c = 0.f;
    if (t < 37) {
        float x = (float)(t - 18);
        if (fabsf(x) <= fs) {
            float qq = x / sd;
            e = __expf(-0.5f * qq * qq);
            c = -x / (sd * sd * sd * 6.28318530717958647692f) * e;
        }
    }
    __shared__ float sa[40], sb[40];
    if (t < 37) { sa[t] = e; sb[t] = fabsf(c); }
    __syncthreads();
    __shared__ float Se, Sc;
    if (t == 0) {
        float a = 0.f, d = 0.f;
        for (int i = 0; i < 37; i++) { a += sa[i]; d += sb[i]; }
        Se = a; Sc = d;
    }
    __syncthreads();
    if (t < 37) {
        wsf[OFF_EH + b * 37 + t] = e / Se;
        wsf[OFF_CH + b * 37 + t] = c / Sc;
    }
}

// ---------------- horizontal pass: batch -> xg (on the fly) -> t0..t3 ----------------
// Block = 4 rows x 512 cols. 8-px sliding window per thread, float4 LDS reads.
__global__ __launch_bounds__(256) void horiz_kernel(const float* __restrict__ batch,
                                                    const float* __restrict__ gcm,
                                                    const float* __restrict__ ehat,
                                                    const float* __restrict__ chat,
                                                    float* __restrict__ t) {
    __shared__ float xr[4][3][556];        // [row][xg-ch][col: idx = 18 + gw], 26,688 B
    int tx = threadIdx.x;
    int h0 = blockIdx.x * 4;
    int b  = blockIdx.y;
    const float* pb = batch + (size_t)(b * 3) * PIX;
    float g0 = gcm[0], g1 = gcm[1], g2 = gcm[2];
    float g3 = gcm[3], g4 = gcm[4], g5 = gcm[5];
    float g6 = gcm[6], g7 = gcm[7], g8 = gcm[8];
    for (int i = tx; i < 4 * 548; i += 256) {
        int r = i / 548, c = i - r * 548;
        int gw = c - 18;
        float v0 = 0.f, v1 = 0.f, v2 = 0.f;
        if (gw >= 0 && gw < WW) {
            size_t p = (size_t)(h0 + r) * WW + gw;
            v0 = pb[p]; v1 = pb[(size_t)PIX + p]; v2 = pb[2 * (size_t)PIX + p];
        }
        xr[r][0][c] = g0 * v0 + g1 * v1 + g2 * v2;
        xr[r][1][c] = g3 * v0 + g4 * v1 + g5 * v2;
        xr[r][2][c] = g6 * v0 + g7 * v1 + g8 * v2;
    }
    __syncthreads();
    int r = tx >> 6, colbase = (tx & 63) * 8;
    const float* eh = ehat + b * 37; const float* ch = chat + b * 37;
    float a0[8] = {}, a1[8] = {}, a2[8] = {}, a3[8] = {};
#pragma unroll
    for (int k4 = 0; k4 < 11; k4++) {
        float4 x0 = *(const float4*)&xr[r][0][colbase + k4 * 4];
        float4 x1 = *(const float4*)&xr[r][1][colbase + k4 * 4];
        float4 x2 = *(const float4*)&xr[r][2][colbase + k4 * 4];
        const float* s0 = (const float*)&x0;
        const float* s1 = (const float*)&x1;
        const float* s2 = (const float*)&x2;
#pragma unroll
        for (int s = 0; s < 4; s++) {
            int kk = k4 * 4 + s;
#pragma unroll
            for (int i = 0; i < 8; i++) {
                int k = kk - i;
                if (k >= 0 && k < 37) {          // compile-time after unroll
                    float ce = eh[k], cc = ch[k];
                    a0[i] += ce * s0[s]; a1[i] += ce * s1[s];
                    a2[i] += ce * s2[s]; a3[i] += cc * s0[s];
                }
            }
        }
    }
    const size_t PL = (size_t)BN * PIX;
    size_t p = (size_t)b * PIX + (size_t)(h0 + r) * WW + colbase;
    *(float4*)&t[0 * PL + p]     = make_float4(a0[0], a0[1], a0[2], a0[3]);
    *(float4*)&t[0 * PL + p + 4] = make_float4(a0[4], a0[5], a0[6], a0[7]);
    *(float4*)&t[1 * PL + p]     = make_float4(a1[0], a1[1], a1[2], a1[3]);
    *(float4*)&t[1 * PL + p + 4] = make_float4(a1[4], a1[5], a1[6], a1[7]);
    *(float4*)&t[2 * PL + p]     = make_float4(a2[0], a2[1], a2[2], a2[3]);
    *(float4*)&t[2 * PL + p + 4] = make_float4(a2[4], a2[5], a2[6], a2[7]);
    *(float4*)&t[3 * PL + p]     = make_float4(a3[0], a3[1], a3[2], a3[3]);
    *(float4*)&t[3 * PL + p + 4] = make_float4(a3[4], a3[5], a3[6], a3[7]);
}

// ---------------- vertical pass + final math -> out ch0,1,5 (8-row sliding/thread) ----------------
__global__ __launch_bounds__(256) void vert_kernel(const float* __restrict__ t,
                                                   const float* __restrict__ ehat,
                                                   const float* __restrict__ chat,
                                                   float* __restrict__ out) {
    int tx = threadIdx.x;
    int j = blockIdx.x * 64 + (tx & 63);
    int r0 = blockIdx.y * 32 + (tx >> 6) * 8;
    int b = blockIdx.z;
    const float* eh = ehat + b * 37; const float* ch = chat + b * 37;
    const size_t PL = (size_t)BN * PIX;
    const float* t0 = t + (size_t)b * PIX;
    float E[8] = {}, Ex[8] = {}, Ey[8] = {}, El[8] = {}, Ell[8] = {};
#pragma unroll
    for (int kk = 0; kk < 44; kk++) {
        int gr = r0 - 18 + kk;
        if (gr >= 0 && gr < HH) {
            size_t idx = (size_t)gr * WW + j;
            float v0 = t0[idx], v1 = t0[PL + idx], v2 = t0[2 * PL + idx], v3 = t0[3 * PL + idx];
#pragma unroll
            for (int i = 0; i < 8; i++) {
                int k = kk - i;
                if (k >= 0 && k < 37) {
                    float ce = eh[k], cc = ch[k];
                    E[i] += ce * v0; Ex[i] += cc * v0; Ey[i] += ce * v3;
                    El[i] += ce * v1; Ell[i] += ce * v2;
                }
            }
        }
    }
#pragma unroll
    for (int i = 0; i < 8; i++) {
        int h = r0 + i;
        float Hf = atanf(El[i] / (Ell[i] + EPSF));
        float S = logf((El[i] * El[i] + Ell[i] * Ell[i]) / (E[i] * E[i] + EPSF) + EPSF);
        float rx = Ex[i] / (E[i] + EPSF), ry = Ey[i] / (E[i] + EPSF);
        float Wv = atanf(rx * rx + ry * ry);
        size_t base = (size_t)(b * 6) * PIX + (size_t)h * WW + j;
        out[base] = Hf;
        out[base + PIX] = S;
        out[base + 5 * (size_t)PIX] = Wv;
    }
}

extern "C" void kernel_launch(void* const* d_in, const int* in_sizes, int n_in,
                              void* d_out, int out_size, void* d_ws, size_t ws_size,
                              hipStream_t stream) {
    const float* batch = (const float*)d_in[0];
    const float* gcm   = (const float*)d_in[1];
    const float* w1    = (const float*)d_in[2];
    const float* b1    = (const float*)d_in[3];
    const float* w2    = (const float*)d_in[4];
    const float* b2    = (const float*)d_in[5];
    const float* w3    = (const float*)d_in[6];
    const float* b3    = (const float*)d_in[7];
    float* out = (float*)d_out;

    if (ws_size < WS_NEEDED) return;

    float* wsf = (float*)d_ws;
    float* tpl = (float*)((char*)d_ws + OFF_TPB);
    float* ehat = wsf + OFF_EH;
    float* chat = wsf + OFF_CH;

    prep_kernel<<<dim3(1), dim3(256), 0, stream>>>(w2, wsf);
    conv12_kernel<<<dim3(8, 32, 8), dim3(256), 0, stream>>>(
        batch, w1, b1, (const unsigned short*)(wsf + OFF_WR), b2, gcm, wsf, out);
    filter_kernel<<<dim3(8), dim3(160), 0, stream>>>(w3, b3, wsf);
    horiz_kernel<<<dim3(128, 8), dim3(256), 0, stream>>>(batch, gcm, ehat, chat, tpl);
    vert_kernel<<<dim3(8, 16, 8), dim3(256), 0, stream>>>(tpl, ehat, chat, out);
}

// Round 8
// 253.209 us; speedup vs baseline: 1.0648x; 1.0648x over previous
//
#include <hip/hip_runtime.h>
#include <hip/hip_bf16.h>

constexpr int BN = 8, HH = 512, WW = 512;
constexpr int PIX = HH * WW;
constexpr float EPSF = 1e-4f;

__device__ __forceinline__ float b2f(__hip_bfloat16 x) { return __bfloat162float(x); }
__device__ __forceinline__ __hip_bfloat16 f2b(float x) { return __float2bfloat16(x); }
__device__ __forceinline__ unsigned short bfbits(float x) {
    union { __hip_bfloat16 b; unsigned short u; } cv; cv.b = f2b(x); return cv.u;
}

typedef __attribute__((ext_vector_type(8))) short bf16x8;   // MFMA A/B frag (4 VGPRs)
typedef __attribute__((ext_vector_type(4))) float f32x4;    // MFMA C/D frag

// ---- workspace float offsets (small region) ----
constexpr int OFF_TOT = 0;       // 8*16 per-image channel totals (atomics)
constexpr int OFF_ROW0 = 128;
constexpr int OFF_ROW1 = 256;
constexpr int OFF_COL0 = 384;
constexpr int OFF_COL1 = 512;
constexpr int OFF_COR = 640;     // corners [b][hi][wi][16]
constexpr int OFF_WR  = 2048;    // A-fragment weights hi(2560 bf16) + lo(2560 bf16)
constexpr int OFF_EH  = 4608;    // 8*37
constexpr int OFF_CH  = 5120;    // 8*37
// ---- big buffers: only tpl (xg computed on the fly in horiz) ----
constexpr size_t OFF_TPB = 65536;                          // tpl fp32 (4 planes)
constexpr size_t TP_BYTES = (size_t)4 * BN * PIX * 4;      // 33,554,432
constexpr size_t WS_NEEDED = OFF_TPB + TP_BYTES;           // ~33.6 MB (134 MB proven)

// ---------------- prep: zero atomic slots, swizzle w2 into hi/lo A-fragments ----------------
// hi = rn-bf16(w), lo = rn-bf16(w - hi): split keeps mean(s) at ~fp32 accuracy (round-4 lesson:
// bf16-only w2 flips the discontinuous ceil() in fs -> pi-flips in Hf).
__global__ void prep_kernel(const float* __restrict__ w2, float* __restrict__ wsf) {
    int t = threadIdx.x;
    for (int i = t; i < 640; i += 256) wsf[i] = 0.f;
    unsigned short* ab = (unsigned short*)(wsf + OFF_WR);
    for (int idx = t; idx < 5120; idx += 256) {
        int part = idx / 2560;               // 0 = hi, 1 = lo
        int id = idx - part * 2560;
        int ks = id >> 9, rem = id & 511, lane = rem >> 3, j = id & 7;
        int oc = lane & 15, q = lane >> 4;
        int k = q * 8 + j;
        int tap = 2 * ks + (k >> 4), ic = k & 15;
        float val = (tap <= 8) ? w2[oc * 144 + ic * 9 + tap] : 0.f;
        float hv = b2f(f2b(val));
        ab[idx] = (part == 0) ? bfbits(val) : bfbits(val - hv);
    }
}

// conv1 for one pixel given its 27-value receptive field -> packed bf16 pair words
__device__ __forceinline__ void conv1_px(const float v[27], const float* __restrict__ w1,
                                         const float* __restrict__ b1, unsigned int u[8]) {
    float o[16];
#pragma unroll
    for (int oc = 0; oc < 16; oc++) {
        float a = b1[oc];
#pragma unroll
        for (int j = 0; j < 27; j++) a += v[j] * w1[oc * 27 + j];
        o[oc] = a / (1.f + __expf(-a));
    }
#pragma unroll
    for (int k = 0; k < 8; k++)
        u[k] = (unsigned int)bfbits(o[2 * k]) | ((unsigned int)bfbits(o[2 * k + 1]) << 16);
}

// ---------------- fused conv1+conv2(+RGB) with conv3-mean reduction (unchanged) ----------------
__global__ __launch_bounds__(256) void conv12_kernel(const float* __restrict__ batch,
                                                     const float* __restrict__ w1,
                                                     const float* __restrict__ b1,
                                                     const unsigned short* __restrict__ abuf,
                                                     const float* __restrict__ b2v,
                                                     const float* __restrict__ gcm,
                                                     float* __restrict__ wsf,
                                                     float* __restrict__ out) {
    __shared__ uint4 h1s[18 * 66 * 2];
    __shared__ float part[4][16];

    int tx = threadIdx.x;
    int lane = tx & 63, wave = tx >> 6;
    int n = lane & 15, q = lane >> 4;
    int w0 = blockIdx.x * 64, h0 = blockIdx.y * 16, b = blockIdx.z;
    bool edge = (blockIdx.x == 0) || (blockIdx.x == 7) || (blockIdx.y == 0) || (blockIdx.y == 31);

    union { uint4 u; bf16x8 v; } cv;
    bf16x8 ah[5], al[5];
    const uint4* ab4 = (const uint4*)abuf;
#pragma unroll
    for (int ks = 0; ks < 5; ks++) {
        cv.u = ab4[ks * 64 + lane];       ah[ks] = cv.v;
        cv.u = ab4[320 + ks * 64 + lane]; al[ks] = cv.v;
    }

    const float* pb = batch + (size_t)(b * 3) * PIX;
    for (int i = tx; i < 18 * 66; i += 256) {
        int r = i / 66, c = i - r * 66;
        int gh = h0 - 1 + r, gw = w0 - 1 + c;
        unsigned int u[8];
        if (!edge) {
            const float* p0 = pb + (size_t)(gh - 1) * WW + (gw - 1);
            float v[27];
#pragma unroll
            for (int ic = 0; ic < 3; ic++)
#pragma unroll
                for (int kh = 0; kh < 3; kh++)
#pragma unroll
                    for (int kw = 0; kw < 3; kw++)
                        v[ic * 9 + kh * 3 + kw] = p0[(size_t)ic * PIX + kh * WW + kw];
            conv1_px(v, w1, b1, u);
        } else if (gh >= 0 && gh < HH && gw >= 0 && gw < WW) {
            float v[27];
#pragma unroll
            for (int ic = 0; ic < 3; ic++) {
                const float* p = pb + (size_t)ic * PIX;
#pragma unroll
                for (int kh = 0; kh < 3; kh++) {
                    int hh = gh + kh - 1;
#pragma unroll
                    for (int kw = 0; kw < 3; kw++) {
                        int ww = gw + kw - 1;
                        float x = 0.f;
                        if (hh >= 0 && hh < HH && ww >= 0 && ww < WW) x = p[hh * WW + ww];
                        v[ic * 9 + kh * 3 + kw] = x;
                    }
                }
            }
            conv1_px(v, w1, b1, u);
        } else {
#pragma unroll
            for (int k = 0; k < 8; k++) u[k] = 0u;
        }
        int swz = (c >> 2) & 1;
        int base = i * 2;
        h1s[base + swz]       = make_uint4(u[0], u[1], u[2], u[3]);
        h1s[base + (swz ^ 1)] = make_uint4(u[4], u[5], u[6], u[7]);
    }

    for (int j = tx; j < 1024; j += 256) {
        int rr = j >> 6, ccx = j & 63;
        size_t p = (size_t)(h0 + rr) * WW + (w0 + ccx);
        float v0 = pb[p], v1 = pb[(size_t)PIX + p], v2 = pb[2 * (size_t)PIX + p];
        int mx  = (v0 >= v1 && v0 >= v2) ? 0 : ((v1 >= v2) ? 1 : 2);
        int mx2 = (v2 >= v1 && v2 >= v0) ? 2 : ((v1 >= v0) ? 1 : 0);
        int mn  = (v0 <= v1 && v0 <= v2) ? 0 : ((v1 <= v2) ? 1 : 2);
        int mn2 = (v2 <= v1 && v2 <= v0) ? 2 : ((v1 <= v0) ? 1 : 0);
#pragma unroll
        for (int c = 0; c < 3; c++) {
            float r = 0.5f * ((float)(c == mx) + (float)(c == mx2))
                    - 0.5f * ((float)(c == mn) + (float)(c == mn2));
            out[(size_t)(b * 6 + 2 + c) * PIX + p] = r;
        }
    }
    __syncthreads();

    float tt[4] = {0, 0, 0, 0};
    float cs0[4] = {0, 0, 0, 0};
    float cs1[4] = {0, 0, 0, 0};
    for (int rloc = 0; rloc < 4; rloc++) {
        int row = wave * 4 + rloc;
        int grow = h0 + row;
        f32x4 acc[4] = {{0,0,0,0},{0,0,0,0},{0,0,0,0},{0,0,0,0}};
#pragma unroll
        for (int ks = 0; ks < 5; ks++) {
            int tap = 2 * ks + (q >> 1); if (tap > 8) tap = 8;
            int dh = tap / 3 - 1, dw = tap % 3 - 1;
            int half = q & 1;
            int lr = row + 1 + dh;
#pragma unroll
            for (int t = 0; t < 4; t++) {
                int c = 1 + dw + t * 16 + n;
                cv.u = h1s[(lr * 66 + c) * 2 + (half ^ ((c >> 2) & 1))];
                acc[t] = __builtin_amdgcn_mfma_f32_16x16x32_bf16(ah[ks], cv.v, acc[t], 0, 0, 0);
                acc[t] = __builtin_amdgcn_mfma_f32_16x16x32_bf16(al[ks], cv.v, acc[t], 0, 0, 0);
            }
        }
        float sv[4][4];
#pragma unroll
        for (int t = 0; t < 4; t++)
#pragma unroll
            for (int r = 0; r < 4; r++) {
                float a = acc[t][r] + b2v[q * 4 + r];
                sv[t][r] = a / (1.f + __expf(-a));
            }
#pragma unroll
        for (int r = 0; r < 4; r++) tt[r] += sv[0][r] + sv[1][r] + sv[2][r] + sv[3][r];
        if (grow == 0 || grow == HH - 1) {
            int off = (grow == 0) ? OFF_ROW0 : OFF_ROW1;
#pragma unroll
            for (int r = 0; r < 4; r++) {
                float x = sv[0][r] + sv[1][r] + sv[2][r] + sv[3][r];
#pragma unroll
                for (int d = 1; d < 16; d <<= 1) x += __shfl_xor(x, d, 64);
                if (n == 0) atomicAdd(&wsf[off + b * 16 + q * 4 + r], x);
            }
        }
        if (blockIdx.x == 0 && n == 0)
#pragma unroll
            for (int r = 0; r < 4; r++) cs0[r] += sv[0][r];
        if (blockIdx.x == 7 && n == 15)
#pragma unroll
            for (int r = 0; r < 4; r++) cs1[r] += sv[3][r];
        if ((grow == 0 || grow == HH - 1)) {
            int hi = (grow == 0) ? 0 : 1;
            if (blockIdx.x == 0 && n == 0)
#pragma unroll
                for (int r = 0; r < 4; r++)
                    wsf[OFF_COR + ((b * 2 + hi) * 2 + 0) * 16 + q * 4 + r] = sv[0][r];
            if (blockIdx.x == 7 && n == 15)
#pragma unroll
                for (int r = 0; r < 4; r++)
                    wsf[OFF_COR + ((b * 2 + hi) * 2 + 1) * 16 + q * 4 + r] = sv[3][r];
        }
    }
    if (blockIdx.x == 0 && n == 0)
#pragma unroll
        for (int r = 0; r < 4; r++) atomicAdd(&wsf[OFF_COL0 + b * 16 + q * 4 + r], cs0[r]);
    if (blockIdx.x == 7 && n == 15)
#pragma unroll
        for (int r = 0; r < 4; r++) atomicAdd(&wsf[OFF_COL1 + b * 16 + q * 4 + r], cs1[r]);
#pragma unroll
    for (int r = 0; r < 4; r++) {
        float x = tt[r];
#pragma unroll
        for (int d = 1; d < 16; d <<= 1) x += __shfl_xor(x, d, 64);
        tt[r] = x;
    }
    if (n == 0)
#pragma unroll
        for (int r = 0; r < 4; r++) part[wave][q * 4 + r] = tt[r];
    __syncthreads();
    if (tx < 16)
        atomicAdd(&wsf[OFF_TOT + b * 16 + tx],
                  part[0][tx] + part[1][tx] + part[2][tx] + part[3][tx]);
}

// ---------------- filter: assemble mean via edge algebra, build separable taps ----------------
__global__ void filter_kernel(const float* __restrict__ w3, const float* __restrict__ b3,
                              float* __restrict__ wsf) {
    int b = blockIdx.x, t = threadIdx.x;   // 160 threads
    __shared__ float red[160];
    float val = 0.f;
    if (t < 144) {
        int ic = t / 9, tap = t % 9, kh = tap / 3, kw = tap % 3;
        float T = wsf[OFF_TOT + b * 16 + ic];
        int hi = -1, wi = -1;
        if (kh == 0) { T -= wsf[OFF_ROW1 + b * 16 + ic]; hi = 1; }
        else if (kh == 2) { T -= wsf[OFF_ROW0 + b * 16 + ic]; hi = 0; }
        if (kw == 0) { T -= wsf[OFF_COL1 + b * 16 + ic]; wi = 1; }
        else if (kw == 2) { T -= wsf[OFF_COL0 + b * 16 + ic]; wi = 0; }
        if (hi >= 0 && wi >= 0) T += wsf[OFF_COR + ((b * 2 + hi) * 2 + wi) * 16 + ic];
        val = w3[t] * T;
    }
    red[t] = val;
    __syncthreads();
    __shared__ float sh_mean;
    if (t == 0) {
        float S = 0.f;
        for (int i = 0; i < 144; i++) S += red[i];
        sh_mean = b3[0] + S * (1.f / (float)PIX);
    }
    __syncthreads();
    float scale = fminf(2.5f, fmaxf(-2.5f, sh_mean));
    float sd = exp2f(scale);
    float fs = ceilf(3.f * sd + 0.5f);
    float e = 0.f, c = 0.f;
    if (t < 37) {
        float x = (float)(t - 18);
        if (fabsf(x) <= fs) {
            float qq = x / sd;
            e = __expf(-0.5f * qq * qq);
            c = -x / (sd * sd * sd * 6.28318530717958647692f) * e;
        }
    }
    __shared__ float sa[40], sb[40];
    if (t < 37) { sa[t] = e; sb[t] = fabsf(c); }
    __syncthreads();
    __shared__ float Se, Sc;
    if (t == 0) {
        float a = 0.f, d = 0.f;
        for (int i = 0; i < 37; i++) { a += sa[i]; d += sb[i]; }
        Se = a; Sc = d;
    }
    __syncthreads();
    if (t < 37) {
        wsf[OFF_EH + b * 37 + t] = e / Se;
        wsf[OFF_CH + b * 37 + t] = c / Sc;
    }
}

// ---------------- horizontal pass: batch -> xg (on the fly) -> t0..t3 ----------------
// Block = 2 rows x 512 cols, 4 px/thread sliding window. Skewed LDS (+1 word per 32)
// breaks the stride-4 8-way bank conflict. Small live set: 16 accumulators, no spill.
__device__ __forceinline__ int skw(int c) { return c + (c >> 5); }
__global__ __launch_bounds__(256, 4) void horiz_kernel(const float* __restrict__ batch,
                                                       const float* __restrict__ gcm,
                                                       const float* __restrict__ ehat,
                                                       const float* __restrict__ chat,
                                                       float* __restrict__ t) {
    __shared__ float xr[2][3][566];        // skewed: logical col 0..547 -> skw(c)
    int tx = threadIdx.x;
    int h0 = blockIdx.x * 2;
    int b  = blockIdx.y;
    const float* pb = batch + (size_t)(b * 3) * PIX;
    float g0 = gcm[0], g1 = gcm[1], g2 = gcm[2];
    float g3 = gcm[3], g4 = gcm[4], g5 = gcm[5];
    float g6 = gcm[6], g7 = gcm[7], g8 = gcm[8];
    for (int i = tx; i < 2 * 548; i += 256) {
        int r = i / 548, c = i - r * 548;
        int gw = c - 18;
        float v0 = 0.f, v1 = 0.f, v2 = 0.f;
        if (gw >= 0 && gw < WW) {
            size_t p = (size_t)(h0 + r) * WW + gw;
            v0 = pb[p]; v1 = pb[(size_t)PIX + p]; v2 = pb[2 * (size_t)PIX + p];
        }
        int cs = skw(c);
        xr[r][0][cs] = g0 * v0 + g1 * v1 + g2 * v2;
        xr[r][1][cs] = g3 * v0 + g4 * v1 + g5 * v2;
        xr[r][2][cs] = g6 * v0 + g7 * v1 + g8 * v2;
    }
    __syncthreads();
    int r = tx >> 7, colbase = (tx & 127) * 4;
    const float* eh = ehat + b * 37; const float* ch = chat + b * 37;
    float a0[4] = {}, a1[4] = {}, a2[4] = {}, a3[4] = {};
#pragma unroll 4
    for (int kk = 0; kk < 40; kk++) {
        int cs = skw(colbase + kk);
        float x0 = xr[r][0][cs], x1 = xr[r][1][cs], x2 = xr[r][2][cs];
#pragma unroll
        for (int i = 0; i < 4; i++) {
            int k = kk - i;
            if (k >= 0 && k < 37) {          // compile-time after unroll
                float ce = eh[k], cc = ch[k];
                a0[i] += ce * x0; a1[i] += ce * x1;
                a2[i] += ce * x2; a3[i] += cc * x0;
            }
        }
    }
    const size_t PL = (size_t)BN * PIX;
    size_t p = (size_t)b * PIX + (size_t)(h0 + r) * WW + colbase;
    *(float4*)&t[0 * PL + p] = make_float4(a0[0], a0[1], a0[2], a0[3]);
    *(float4*)&t[1 * PL + p] = make_float4(a1[0], a1[1], a1[2], a1[3]);
    *(float4*)&t[2 * PL + p] = make_float4(a2[0], a2[1], a2[2], a2[3]);
    *(float4*)&t[3 * PL + p] = make_float4(a3[0], a3[1], a3[2], a3[3]);
}

// ---------------- vertical pass + final math -> out ch0,1,5 (4-row sliding/thread) ----------------
__global__ __launch_bounds__(256, 4) void vert_kernel(const float* __restrict__ t,
                                                      const float* __restrict__ ehat,
                                                      const float* __restrict__ chat,
                                                      float* __restrict__ out) {
    int tx = threadIdx.x;
    int j = blockIdx.x * 64 + (tx & 63);
    int r0 = (blockIdx.y * 4 + (tx >> 6)) * 4;
    int b = blockIdx.z;
    const float* eh = ehat + b * 37; const float* ch = chat + b * 37;
    const size_t PL = (size_t)BN * PIX;
    const float* t0 = t + (size_t)b * PIX;
    float E[4] = {}, Ex[4] = {}, Ey[4] = {}, El[4] = {}, Ell[4] = {};
#pragma unroll 4
    for (int kk = 0; kk < 40; kk++) {
        int gr = r0 - 18 + kk;
        if (gr >= 0 && gr < HH) {
            size_t idx = (size_t)gr * WW + j;
            float v0 = t0[idx], v1 = t0[PL + idx], v2 = t0[2 * PL + idx], v3 = t0[3 * PL + idx];
#pragma unroll
            for (int i = 0; i < 4; i++) {
                int k = kk - i;
                if (k >= 0 && k < 37) {
                    float ce = eh[k], cc = ch[k];
                    E[i] += ce * v0; Ex[i] += cc * v0; Ey[i] += ce * v3;
                    El[i] += ce * v1; Ell[i] += ce * v2;
                }
            }
        }
    }
#pragma unroll
    for (int i = 0; i < 4; i++) {
        int h = r0 + i;
        float Hf = atanf(El[i] / (Ell[i] + EPSF));
        float S = logf((El[i] * El[i] + Ell[i] * Ell[i]) / (E[i] * E[i] + EPSF) + EPSF);
        float rx = Ex[i] / (E[i] + EPSF), ry = Ey[i] / (E[i] + EPSF);
        float Wv = atanf(rx * rx + ry * ry);
        size_t base = (size_t)(b * 6) * PIX + (size_t)h * WW + j;
        out[base] = Hf;
        out[base + PIX] = S;
        out[base + 5 * (size_t)PIX] = Wv;
    }
}

extern "C" void kernel_launch(void* const* d_in, const int* in_sizes, int n_in,
                              void* d_out, int out_size, void* d_ws, size_t ws_size,
                              hipStream_t stream) {
    const float* batch = (const float*)d_in[0];
    const float* gcm   = (const float*)d_in[1];
    const float* w1    = (const float*)d_in[2];
    const float* b1    = (const float*)d_in[3];
    const float* w2    = (const float*)d_in[4];
    const float* b2    = (const float*)d_in[5];
    const float* w3    = (const float*)d_in[6];
    const float* b3    = (const float*)d_in[7];
    float* out = (float*)d_out;

    if (ws_size < WS_NEEDED) return;

    float* wsf = (float*)d_ws;
    float* tpl = (float*)((char*)d_ws + OFF_TPB);
    float* ehat = wsf + OFF_EH;
    float* chat = wsf + OFF_CH;

    prep_kernel<<<dim3(1), dim3(256), 0, stream>>>(w2, wsf);
    conv12_kernel<<<dim3(8, 32, 8), dim3(256), 0, stream>>>(
        batch, w1, b1, (const unsigned short*)(wsf + OFF_WR), b2, gcm, wsf, out);
    filter_kernel<<<dim3(8), dim3(160), 0, stream>>>(w3, b3, wsf);
    horiz_kernel<<<dim3(256, 8), dim3(256), 0, stream>>>(batch, gcm, ehat, chat, tpl);
    vert_kernel<<<dim3(8, 32, 8), dim3(256), 0, stream>>>(tpl, ehat, chat, out);
}